// Round 10
// baseline (100.195 us; speedup 1.0000x reference)
//
#include <hip/hip_runtime.h>

#define HW  262144     // 512*512
#define HW4 65536      // HW/4
#define NPATCH 16384   // 16 * 32 * 32

// ws layout (floats):
// [0]                : exposure sum of (patch_mean - E)^2
// [1]                : tv vertical sum
// [2]                : tv horizontal sum
// [3 .. 51)          : color channel sums, index 3 + b*3 + c   (48)
// [51 .. 51+128*11)  : semantic stats, index 51 + (b*8+k)*11 + s
//                      s: 0=sumM 1=sumM2 2..4=sRM[c] 5..7=sRM2[c] 8..10=sR2M2[c]
#define WS_FLOATS (3 + 48 + 128*11)

// 128 groups x 13 roles {8 sem, 2 L-pair, 3 color}; all blocks 512 threads.
// sem = 1024 blocks (8192 waves -> fills the 8192 wave slots), L-pair = 256,
// color = 384. Interleaved so light blocks co-schedule with sem (no tail).
#define TOTAL_BLOCKS (13 * 128)

__device__ __forceinline__ float wave_reduce(float x) {
#pragma unroll
  for (int o = 32; o >= 1; o >>= 1) x += __shfl_down(x, o);
  return x;
}

// one element update, single k; t-form: t=x*m -> p+=t, q+=t*m, r+=t*t
#define CEL(x0v, x1v, x2v, mmv)                                                \
  {                                                                            \
    float _m = (mmv), _m2 = _m * _m;                                           \
    float _t0 = (x0v) * _m, _t1 = (x1v) * _m, _t2 = (x2v) * _m;                \
    an += _m;  an2 += _m2;                                                     \
    ap0 += _t0;  ap1 += _t1;  ap2 += _t2;                                      \
    aq0 += _t0 * _m; aq1 += _t1 * _m; aq2 += _t2 * _m;                         \
    ar0 += _t0 * _t0; ar1 += _t1 * _t1; ar2 += _t2 * _t2;                      \
  }

__global__ __launch_bounds__(512) void mega_kernel(
    const float* __restrict__ L, const float* __restrict__ R,
    const float* __restrict__ I, const float* __restrict__ M,
    float* __restrict__ ws) {
  const int bid = blockIdx.x;
  const int tid = threadIdx.x;
  const int lane = tid & 63;
  const int grp = bid / 13;
  const int role = bid - grp * 13;

  if (role < 8) {
    // ------------- semantic stats: R (B,3,H,W) x M (B,8,H,W) ---------------
    // Stream-per-wave topology (R8 winner): wave wv owns mask channel k=wv,
    // reads its M plane contiguously; R staged per block into LDS (512-f4
    // window x 3 planes = 24 KB) and shared by all 8 waves. R10 change:
    // 1024 sem blocks x 2 windows (was 512 x 4) so the sem phase alone can
    // occupy all 8192 wave slots.
    const int sidx = grp * 8 + role;   // 0..1023
    const int b = sidx >> 6;           // 0..15
    const int wb = sidx & 63;          // 0..63 -> windows 2wb, 2wb+1
    const int wv = tid >> 6;           // 0..7 == k
    const float4* R4 = (const float4*)(R + (size_t)b * 3 * HW);
    const float4* M4k = (const float4*)(M + ((size_t)b * 8 + wv) * HW);
    __shared__ float4 rl[1536];        // [plane][512]

    float an = 0.f, an2 = 0.f, ap0 = 0.f, ap1 = 0.f, ap2 = 0.f;
    float aq0 = 0.f, aq1 = 0.f, aq2 = 0.f, ar0 = 0.f, ar1 = 0.f, ar2 = 0.f;

    for (int w2 = 0; w2 < 2; ++w2) {
      const int base = (wb * 2 + w2) * 512;  // window start (f4 units)
      // stage R window: 1536 f4 by 512 threads = 3 each (coalesced)
#pragma unroll
      for (int r = 0; r < 3; ++r) {
        int j = tid + r * 512;
        rl[j] = R4[(j >> 9) * HW4 + base + (j & 511)];
      }
      __syncthreads();
      // consume: wave wv reads its M plane, 8 chunks rotated by wv
#pragma unroll 4
      for (int c = 0; c < 8; ++c) {
        int o = (((c + wv) & 7) << 6) + lane;
        float4 m = M4k[base + o];
        float4 r0 = rl[o], r1 = rl[512 + o], r2 = rl[1024 + o];
        CEL(r0.x, r1.x, r2.x, m.x)
        CEL(r0.y, r1.y, r2.y, m.y)
        CEL(r0.z, r1.z, r2.z, m.z)
        CEL(r0.w, r1.w, r2.w, m.w)
      }
      __syncthreads();  // protect LDS before next stage
    }

    float* dst = ws + 51 + (size_t)((b * 8 + wv) * 11);
    float v;
    v = wave_reduce(an);  if (lane == 0) atomicAdd(&dst[0], v);
    v = wave_reduce(an2); if (lane == 0) atomicAdd(&dst[1], v);
    v = wave_reduce(ap0); if (lane == 0) atomicAdd(&dst[2], v);
    v = wave_reduce(ap1); if (lane == 0) atomicAdd(&dst[3], v);
    v = wave_reduce(ap2); if (lane == 0) atomicAdd(&dst[4], v);
    v = wave_reduce(aq0); if (lane == 0) atomicAdd(&dst[5], v);
    v = wave_reduce(aq1); if (lane == 0) atomicAdd(&dst[6], v);
    v = wave_reduce(aq2); if (lane == 0) atomicAdd(&dst[7], v);
    v = wave_reduce(ar0); if (lane == 0) atomicAdd(&dst[8], v);
    v = wave_reduce(ar1); if (lane == 0) atomicAdd(&dst[9], v);
    v = wave_reduce(ar2); if (lane == 0) atomicAdd(&dst[10], v);
    return;
  }

  if (role < 10) {
    // ------------- L bands: TV (v+h) + exposure; 2 bands per block ---------
    const int lidx = grp * 2 + (role - 8);  // 0..255
    const int sub = tid >> 8;               // 0/1 -> band
    const int stid = tid & 255;
    const int band = lidx * 2 + sub;        // 0..511
    const int b = band >> 5;                // 0..15
    const int pr = band & 31;               // patch row
    const int half = stid >> 7;             // 0..1
    const int c4 = stid & 127;              // f4 column
    const int row0 = pr * 16 + half * 8;
    const float* Lb = L + (size_t)b * HW;
    const float4* L4b = (const float4*)Lb;
    __shared__ float part[2][2][128];
    __shared__ float redv[2][4], redh[2][4];

    float sv = 0.f, sh = 0.f, ps = 0.f;
    float4 cur = L4b[row0 * 128 + c4];
#pragma unroll
    for (int r = 0; r < 8; ++r) {
      sh += fabsf(cur.x - cur.y) + fabsf(cur.y - cur.z) + fabsf(cur.z - cur.w);
      float nx = __shfl_down(cur.x, 1);  // next f4's .x, same row
      if (lane == 63 && c4 < 127) nx = Lb[(row0 + r) * 512 + c4 * 4 + 4];
      if (c4 < 127) sh += fabsf(cur.w - nx);
      ps += (cur.x + cur.y) + (cur.z + cur.w);
      int nr = row0 + r + 1;
      if (nr < 512) {
        float4 nxt = L4b[nr * 128 + c4];
        sv += fabsf(cur.x - nxt.x) + fabsf(cur.y - nxt.y) +
              fabsf(cur.z - nxt.z) + fabsf(cur.w - nxt.w);
        cur = nxt;
      }
    }
    part[sub][half][c4] = ps;
    sv = wave_reduce(sv);
    sh = wave_reduce(sh);
    int wv2 = stid >> 6;  // wave within sub-block: 0..3
    if (lane == 0) { redv[sub][wv2] = sv; redh[sub][wv2] = sh; }
    __syncthreads();
    if (stid == 0) {
      atomicAdd(&ws[1],
                (redv[sub][0] + redv[sub][1]) + (redv[sub][2] + redv[sub][3]));
      atomicAdd(&ws[2],
                (redh[sub][0] + redh[sub][1]) + (redh[sub][2] + redh[sub][3]));
    }
    float e = 0.f;
    if (stid < 32) {  // patch p = stid covers f4 cols [4p, 4p+4)
      float s = 0.f;
#pragma unroll
      for (int h = 0; h < 2; ++h)
#pragma unroll
        for (int q = 0; q < 4; ++q) s += part[sub][h][stid * 4 + q];
      float d = s * (1.0f / 256.0f) - 0.6f;
      e = d * d;
    }
    e = wave_reduce(e);
    if (stid == 0) atomicAdd(&ws[0], e);
    return;
  }

  {
    // ------------- color: per (b,c) channel sums of I_enh ------------------
    const int cid = grp * 3 + (role - 10);  // 0..383
    const int slice = cid >> 3;             // 0..47
    const int xb8 = cid & 7;
    const float4* I4 = (const float4*)(I + (size_t)slice * HW);
    float s = 0.f;
    int i = xb8 * 8192 + tid;
#pragma unroll 4
    for (int it = 0; it < 16; ++it, i += 512) {
      float4 v = I4[i];
      s += (v.x + v.y) + (v.z + v.w);
    }
    s = wave_reduce(s);
    __shared__ float red[8];
    int wv = tid >> 6;
    if (lane == 0) red[wv] = s;
    __syncthreads();
    if (tid == 0) {
      float t = ((red[0] + red[1]) + (red[2] + red[3])) +
                ((red[4] + red[5]) + (red[6] + red[7]));
      atomicAdd(&ws[3 + slice], t);
    }
  }
}

// ---------------- final combine ----------------
__global__ __launch_bounds__(256) void final_kernel(const float* __restrict__ ws,
                                                    float* __restrict__ out) {
  __shared__ float red[256];
  int t = threadIdx.x;
  float sem = 0.f;
  if (t < 128) {
    const float* s = ws + 51 + t * 11;
    float n = s[0] + 1e-6f;
    float v = 0.f;
#pragma unroll
    for (int c = 0; c < 3; ++c) {
      float mean = s[2 + c] / n;
      v += s[8 + c] - 2.0f * mean * s[5 + c] + mean * mean * s[1];
    }
    sem = v / n;
  }
  red[t] = sem;
  __syncthreads();
  for (int s = 128; s > 0; s >>= 1) {
    if (t < s) red[t] += red[t + s];
    __syncthreads();
  }
  if (t == 0) {
    float L_sem = red[0] / 16.0f;
    float L_exp = ws[0] / (float)NPATCH;
    float L_tv = ws[1] / (16.0f * 511.0f * 512.0f) +
                 ws[2] / (16.0f * 512.0f * 511.0f);
    float L_color = 0.f;
#pragma unroll
    for (int b = 0; b < 16; ++b) {
      float r = ws[3 + b * 3 + 0] * (1.0f / (float)HW);
      float g = ws[3 + b * 3 + 1] * (1.0f / (float)HW);
      float bl = ws[3 + b * 3 + 2] * (1.0f / (float)HW);
      L_color += (r - g) * (r - g) + (r - bl) * (r - bl) + (g - bl) * (g - bl);
    }
    L_color *= (1.0f / 16.0f);
    out[0] = 10.0f * L_exp + 1.0f * L_tv + 10.0f * L_color + 50.0f * L_sem;
  }
}

extern "C" void kernel_launch(void* const* d_in, const int* in_sizes, int n_in,
                              void* d_out, int out_size, void* d_ws, size_t ws_size,
                              hipStream_t stream) {
  const float* L     = (const float*)d_in[0];  // (16,1,512,512)
  const float* R     = (const float*)d_in[1];  // (16,3,512,512)
  const float* I_enh = (const float*)d_in[2];  // (16,3,512,512)
  const float* M     = (const float*)d_in[3];  // (16,8,512,512)
  float* out = (float*)d_out;
  float* ws  = (float*)d_ws;

  (void)hipMemsetAsync(d_ws, 0, WS_FLOATS * sizeof(float), stream);
  mega_kernel<<<TOTAL_BLOCKS, 512, 0, stream>>>(L, R, I_enh, M, ws);
  final_kernel<<<1, 256, 0, stream>>>(ws, out);
}

// Round 11
// 87.480 us; speedup vs baseline: 1.1453x; 1.1453x over previous
//
#include <hip/hip_runtime.h>

#define HW  262144     // 512*512
#define HW4 65536      // HW/4
#define NPATCH 16384   // 16 * 32 * 32

// ws layout (floats):
// [0]                : exposure sum of (patch_mean - E)^2
// [1]                : tv vertical sum
// [2]                : tv horizontal sum
// [3 .. 51)          : color channel sums, index 3 + b*3 + c   (48)
// [51 .. 51+128*11)  : semantic stats, index 51 + (b*8+k)*11 + s
//                      s: 0=sumM 1=sumM2 2..4=sRM[c] 5..7=sRM2[c] 8..10=sR2M2[c]
#define WS_FLOATS (3 + 48 + 128*11)

// contiguous roles (R8 layout — interleave regressed in R10); 512-thr blocks
#define SEM_BLOCKS   512    // 16 images x 32 blocks; 4 windows of 512 f4 each
#define LBAND_BLOCKS 256    // 2 bands per block
#define COLOR_BLOCKS 384
#define TOTAL_BLOCKS (SEM_BLOCKS + LBAND_BLOCKS + COLOR_BLOCKS)

__device__ __forceinline__ float wave_reduce(float x) {
#pragma unroll
  for (int o = 32; o >= 1; o >>= 1) x += __shfl_down(x, o);
  return x;
}

// one element update, single k; t-form: t=x*m -> p+=t, q+=t*m, r+=t*t
#define CEL(x0v, x1v, x2v, mmv)                                                \
  {                                                                            \
    float _m = (mmv), _m2 = _m * _m;                                           \
    float _t0 = (x0v) * _m, _t1 = (x1v) * _m, _t2 = (x2v) * _m;                \
    an += _m;  an2 += _m2;                                                     \
    ap0 += _t0;  ap1 += _t1;  ap2 += _t2;                                      \
    aq0 += _t0 * _m; aq1 += _t1 * _m; aq2 += _t2 * _m;                         \
    ar0 += _t0 * _t0; ar1 += _t1 * _t1; ar2 += _t2 * _t2;                      \
  }

__global__ __launch_bounds__(512) void mega_kernel(
    const float* __restrict__ L, const float* __restrict__ R,
    const float* __restrict__ I, const float* __restrict__ M,
    float* __restrict__ ws) {
  const int bid = blockIdx.x;
  const int tid = threadIdx.x;
  const int lane = tid & 63;

  if (bid < SEM_BLOCKS) {
    // ------------- semantic stats: R (B,3,H,W) x M (B,8,H,W) ---------------
    // R8 topology (champion): wave wv owns mask channel k=wv, reads its M
    // plane contiguously; R staged per block into LDS, shared by all 8 waves.
    // R11 change: double-buffered LDS + async stage split (T14): issue next
    // window's R loads at top of consume (latency hides under M loads+FMA),
    // write them to the other buffer after consume, ONE barrier per window.
    const int b = bid >> 5;            // 0..15
    const int wb = bid & 31;           // 0..31 -> windows 4wb .. 4wb+3
    const int wv = tid >> 6;           // 0..7 == k
    const float4* R4 = (const float4*)(R + (size_t)b * 3 * HW);
    const float4* M4k = (const float4*)(M + ((size_t)b * 8 + wv) * HW);
    __shared__ float4 rl[2][1536];     // [buf][plane*512 + off]

    float an = 0.f, an2 = 0.f, ap0 = 0.f, ap1 = 0.f, ap2 = 0.f;
    float aq0 = 0.f, aq1 = 0.f, aq2 = 0.f, ar0 = 0.f, ar1 = 0.f, ar2 = 0.f;

    // prologue: stage window 0 into buf 0
    {
      const int base0 = (wb * 4) * 512;
      float4 t0 = R4[base0 + tid];
      float4 t1 = R4[HW4 + base0 + tid];
      float4 t2 = R4[2 * HW4 + base0 + tid];
      rl[0][tid] = t0; rl[0][512 + tid] = t1; rl[0][1024 + tid] = t2;
    }
    __syncthreads();

#pragma unroll
    for (int w2 = 0; w2 < 4; ++w2) {
      const int buf = w2 & 1;
      const int base = (wb * 4 + w2) * 512;
      float4 s0, s1, s2;
      if (w2 < 3) {  // issue next window's stage loads EARLY
        const int nb = base + 512;
        s0 = R4[nb + tid];
        s1 = R4[HW4 + nb + tid];
        s2 = R4[2 * HW4 + nb + tid];
      }
      // consume current window: wave wv reads its M plane, chunks rotated
#pragma unroll 4
      for (int c = 0; c < 8; ++c) {
        int o = (((c + wv) & 7) << 6) + lane;
        float4 m = M4k[base + o];
        float4 r0 = rl[buf][o], r1 = rl[buf][512 + o], r2 = rl[buf][1024 + o];
        CEL(r0.x, r1.x, r2.x, m.x)
        CEL(r0.y, r1.y, r2.y, m.y)
        CEL(r0.z, r1.z, r2.z, m.z)
        CEL(r0.w, r1.w, r2.w, m.w)
      }
      if (w2 < 3) {  // write staged regs LATE into the other buffer
        rl[buf ^ 1][tid] = s0;
        rl[buf ^ 1][512 + tid] = s1;
        rl[buf ^ 1][1024 + tid] = s2;
      }
      __syncthreads();  // one barrier per window
    }

    float* dst = ws + 51 + (size_t)((b * 8 + wv) * 11);
    float v;
    v = wave_reduce(an);  if (lane == 0) atomicAdd(&dst[0], v);
    v = wave_reduce(an2); if (lane == 0) atomicAdd(&dst[1], v);
    v = wave_reduce(ap0); if (lane == 0) atomicAdd(&dst[2], v);
    v = wave_reduce(ap1); if (lane == 0) atomicAdd(&dst[3], v);
    v = wave_reduce(ap2); if (lane == 0) atomicAdd(&dst[4], v);
    v = wave_reduce(aq0); if (lane == 0) atomicAdd(&dst[5], v);
    v = wave_reduce(aq1); if (lane == 0) atomicAdd(&dst[6], v);
    v = wave_reduce(aq2); if (lane == 0) atomicAdd(&dst[7], v);
    v = wave_reduce(ar0); if (lane == 0) atomicAdd(&dst[8], v);
    v = wave_reduce(ar1); if (lane == 0) atomicAdd(&dst[9], v);
    v = wave_reduce(ar2); if (lane == 0) atomicAdd(&dst[10], v);
    return;
  }

  if (bid < SEM_BLOCKS + LBAND_BLOCKS) {
    // ------------- L bands: TV (v+h) + exposure; 2 bands per block ---------
    const int lidx = bid - SEM_BLOCKS;      // 0..255
    const int sub = tid >> 8;               // 0/1 -> band
    const int stid = tid & 255;
    const int band = lidx * 2 + sub;        // 0..511
    const int b = band >> 5;                // 0..15
    const int pr = band & 31;               // patch row
    const int half = stid >> 7;             // 0..1
    const int c4 = stid & 127;              // f4 column
    const int row0 = pr * 16 + half * 8;
    const float* Lb = L + (size_t)b * HW;
    const float4* L4b = (const float4*)Lb;
    __shared__ float part[2][2][128];
    __shared__ float redv[2][4], redh[2][4];

    float sv = 0.f, sh = 0.f, ps = 0.f;
    float4 cur = L4b[row0 * 128 + c4];
#pragma unroll
    for (int r = 0; r < 8; ++r) {
      sh += fabsf(cur.x - cur.y) + fabsf(cur.y - cur.z) + fabsf(cur.z - cur.w);
      float nx = __shfl_down(cur.x, 1);  // next f4's .x, same row
      if (lane == 63 && c4 < 127) nx = Lb[(row0 + r) * 512 + c4 * 4 + 4];
      if (c4 < 127) sh += fabsf(cur.w - nx);
      ps += (cur.x + cur.y) + (cur.z + cur.w);
      int nr = row0 + r + 1;
      if (nr < 512) {
        float4 nxt = L4b[nr * 128 + c4];
        sv += fabsf(cur.x - nxt.x) + fabsf(cur.y - nxt.y) +
              fabsf(cur.z - nxt.z) + fabsf(cur.w - nxt.w);
        cur = nxt;
      }
    }
    part[sub][half][c4] = ps;
    sv = wave_reduce(sv);
    sh = wave_reduce(sh);
    int wv2 = stid >> 6;  // wave within sub-block: 0..3
    if (lane == 0) { redv[sub][wv2] = sv; redh[sub][wv2] = sh; }
    __syncthreads();
    if (stid == 0) {
      atomicAdd(&ws[1],
                (redv[sub][0] + redv[sub][1]) + (redv[sub][2] + redv[sub][3]));
      atomicAdd(&ws[2],
                (redh[sub][0] + redh[sub][1]) + (redh[sub][2] + redh[sub][3]));
    }
    float e = 0.f;
    if (stid < 32) {  // patch p = stid covers f4 cols [4p, 4p+4)
      float s = 0.f;
#pragma unroll
      for (int h = 0; h < 2; ++h)
#pragma unroll
        for (int q = 0; q < 4; ++q) s += part[sub][h][stid * 4 + q];
      float d = s * (1.0f / 256.0f) - 0.6f;
      e = d * d;
    }
    e = wave_reduce(e);
    if (stid == 0) atomicAdd(&ws[0], e);
    return;
  }

  {
    // ------------- color: per (b,c) channel sums of I_enh ------------------
    const int cid = bid - (SEM_BLOCKS + LBAND_BLOCKS);  // 0..383
    const int slice = cid >> 3;             // 0..47
    const int xb8 = cid & 7;
    const float4* I4 = (const float4*)(I + (size_t)slice * HW);
    float s = 0.f;
    int i = xb8 * 8192 + tid;
#pragma unroll 4
    for (int it = 0; it < 16; ++it, i += 512) {
      float4 v = I4[i];
      s += (v.x + v.y) + (v.z + v.w);
    }
    s = wave_reduce(s);
    __shared__ float red[8];
    int wv = tid >> 6;
    if (lane == 0) red[wv] = s;
    __syncthreads();
    if (tid == 0) {
      float t = ((red[0] + red[1]) + (red[2] + red[3])) +
                ((red[4] + red[5]) + (red[6] + red[7]));
      atomicAdd(&ws[3 + slice], t);
    }
  }
}

// ---------------- final combine ----------------
__global__ __launch_bounds__(256) void final_kernel(const float* __restrict__ ws,
                                                    float* __restrict__ out) {
  __shared__ float red[256];
  int t = threadIdx.x;
  float sem = 0.f;
  if (t < 128) {
    const float* s = ws + 51 + t * 11;
    float n = s[0] + 1e-6f;
    float v = 0.f;
#pragma unroll
    for (int c = 0; c < 3; ++c) {
      float mean = s[2 + c] / n;
      v += s[8 + c] - 2.0f * mean * s[5 + c] + mean * mean * s[1];
    }
    sem = v / n;
  }
  red[t] = sem;
  __syncthreads();
  for (int s = 128; s > 0; s >>= 1) {
    if (t < s) red[t] += red[t + s];
    __syncthreads();
  }
  if (t == 0) {
    float L_sem = red[0] / 16.0f;
    float L_exp = ws[0] / (float)NPATCH;
    float L_tv = ws[1] / (16.0f * 511.0f * 512.0f) +
                 ws[2] / (16.0f * 512.0f * 511.0f);
    float L_color = 0.f;
#pragma unroll
    for (int b = 0; b < 16; ++b) {
      float r = ws[3 + b * 3 + 0] * (1.0f / (float)HW);
      float g = ws[3 + b * 3 + 1] * (1.0f / (float)HW);
      float bl = ws[3 + b * 3 + 2] * (1.0f / (float)HW);
      L_color += (r - g) * (r - g) + (r - bl) * (r - bl) + (g - bl) * (g - bl);
    }
    L_color *= (1.0f / 16.0f);
    out[0] = 10.0f * L_exp + 1.0f * L_tv + 10.0f * L_color + 50.0f * L_sem;
  }
}

extern "C" void kernel_launch(void* const* d_in, const int* in_sizes, int n_in,
                              void* d_out, int out_size, void* d_ws, size_t ws_size,
                              hipStream_t stream) {
  const float* L     = (const float*)d_in[0];  // (16,1,512,512)
  const float* R     = (const float*)d_in[1];  // (16,3,512,512)
  const float* I_enh = (const float*)d_in[2];  // (16,3,512,512)
  const float* M     = (const float*)d_in[3];  // (16,8,512,512)
  float* out = (float*)d_out;
  float* ws  = (float*)d_ws;

  (void)hipMemsetAsync(d_ws, 0, WS_FLOATS * sizeof(float), stream);
  mega_kernel<<<TOTAL_BLOCKS, 512, 0, stream>>>(L, R, I_enh, M, ws);
  final_kernel<<<1, 256, 0, stream>>>(ws, out);
}

// Round 12
// 69.499 us; speedup vs baseline: 1.4417x; 1.2587x over previous
//
#include <hip/hip_runtime.h>

#define HW  262144     // 512*512
#define HW4 65536      // HW/4
#define NPATCH 16384   // 16 * 32 * 32

// ws layout (floats):
// [0]                : exposure sum of (patch_mean - E)^2
// [1]                : tv vertical sum
// [2]                : tv horizontal sum
// [3 .. 51)          : color channel sums, index 3 + b*3 + c   (48)
// [51 .. 51+128*11)  : semantic stats, index 51 + (b*8+k)*11 + s
//                      s: 0=sumM 1=sumM2 2..4=sRM[c] 5..7=sRM2[c] 8..10=sR2M2[c]
#define WS_FLOATS (3 + 48 + 128*11)

// contiguous roles (R8 champion layout); all blocks 512 threads
#define SEM_BLOCKS   512    // 16 images x 32 blocks; 2 windows of 1024 f4 each
#define LBAND_BLOCKS 256    // 2 bands per block
#define COLOR_BLOCKS 384
#define TOTAL_BLOCKS (SEM_BLOCKS + LBAND_BLOCKS + COLOR_BLOCKS)

__device__ __forceinline__ float wave_reduce(float x) {
#pragma unroll
  for (int o = 32; o >= 1; o >>= 1) x += __shfl_down(x, o);
  return x;
}

// async global->LDS, 16B per lane (dwordx4 path, no VGPR round-trip)
#define GLOAD16(gp, lp)                                                        \
  __builtin_amdgcn_global_load_lds(                                            \
      (const __attribute__((address_space(1))) void*)(gp),                     \
      (__attribute__((address_space(3))) void*)(lp), 16, 0, 0)

// one element update, single k; t-form: t=x*m -> p+=t, q+=t*m, r+=t*t
#define CEL(x0v, x1v, x2v, mmv)                                                \
  {                                                                            \
    float _m = (mmv), _m2 = _m * _m;                                           \
    float _t0 = (x0v) * _m, _t1 = (x1v) * _m, _t2 = (x2v) * _m;                \
    an += _m;  an2 += _m2;                                                     \
    ap0 += _t0;  ap1 += _t1;  ap2 += _t2;                                      \
    aq0 += _t0 * _m; aq1 += _t1 * _m; aq2 += _t2 * _m;                         \
    ar0 += _t0 * _t0; ar1 += _t1 * _t1; ar2 += _t2 * _t2;                      \
  }

__global__ __launch_bounds__(512) void mega_kernel(
    const float* __restrict__ L, const float* __restrict__ R,
    const float* __restrict__ I, const float* __restrict__ M,
    float* __restrict__ ws) {
  const int bid = blockIdx.x;
  const int tid = threadIdx.x;
  const int lane = tid & 63;

  if (bid < SEM_BLOCKS) {
    // ------------- semantic stats: R (B,3,H,W) x M (B,8,H,W) ---------------
    // R8 topology (champion): wave wv owns mask channel k=wv, reads its M
    // plane contiguously; R staged per block into LDS (1024-f4 window x 3
    // planes = 48 KB), shared by all 8 waves. R12 change: staging goes
    // through __builtin_amdgcn_global_load_lds (width=16) — async DMA to
    // LDS, no VGPR round-trip, no load->ds_write chain before the barrier.
    // Wave-uniform-dest constraint holds: j = wv*64+lane+r*512 never
    // crosses a 1024-f4 plane boundary within a wave.
    const int b = bid >> 5;            // 0..15
    const int wb = bid & 31;           // 0..31 -> windows 2wb, 2wb+1
    const int wv = tid >> 6;           // 0..7 == k
    const float4* R4 = (const float4*)(R + (size_t)b * 3 * HW);
    const float4* M4k = (const float4*)(M + ((size_t)b * 8 + wv) * HW);
    __shared__ float4 rl[3072];        // [plane][1024]

    float an = 0.f, an2 = 0.f, ap0 = 0.f, ap1 = 0.f, ap2 = 0.f;
    float aq0 = 0.f, aq1 = 0.f, aq2 = 0.f, ar0 = 0.f, ar1 = 0.f, ar2 = 0.f;

    for (int w2 = 0; w2 < 2; ++w2) {
      const int base = (wb * 2 + w2) * 1024;  // window start (f4 units)
      // stage R window: 3072 f4 by 512 threads = 6 x 16B each, async DMA
#pragma unroll
      for (int r = 0; r < 6; ++r) {
        int j = tid + r * 512;
        GLOAD16(&R4[(j >> 10) * HW4 + base + (j & 1023)], &rl[j]);
      }
      __syncthreads();   // compiler drains vmcnt(0) before s_barrier
      // consume: wave wv reads its M plane chunk-rotated
#pragma unroll 4
      for (int c = 0; c < 16; ++c) {
        int o = (((c + 2 * wv) & 15) << 6) + lane;
        float4 m = M4k[base + o];
        float4 r0 = rl[o], r1 = rl[1024 + o], r2 = rl[2048 + o];
        CEL(r0.x, r1.x, r2.x, m.x)
        CEL(r0.y, r1.y, r2.y, m.y)
        CEL(r0.z, r1.z, r2.z, m.z)
        CEL(r0.w, r1.w, r2.w, m.w)
      }
      __syncthreads();  // protect LDS before next stage
    }

    float* dst = ws + 51 + (size_t)((b * 8 + wv) * 11);
    float v;
    v = wave_reduce(an);  if (lane == 0) atomicAdd(&dst[0], v);
    v = wave_reduce(an2); if (lane == 0) atomicAdd(&dst[1], v);
    v = wave_reduce(ap0); if (lane == 0) atomicAdd(&dst[2], v);
    v = wave_reduce(ap1); if (lane == 0) atomicAdd(&dst[3], v);
    v = wave_reduce(ap2); if (lane == 0) atomicAdd(&dst[4], v);
    v = wave_reduce(aq0); if (lane == 0) atomicAdd(&dst[5], v);
    v = wave_reduce(aq1); if (lane == 0) atomicAdd(&dst[6], v);
    v = wave_reduce(aq2); if (lane == 0) atomicAdd(&dst[7], v);
    v = wave_reduce(ar0); if (lane == 0) atomicAdd(&dst[8], v);
    v = wave_reduce(ar1); if (lane == 0) atomicAdd(&dst[9], v);
    v = wave_reduce(ar2); if (lane == 0) atomicAdd(&dst[10], v);
    return;
  }

  if (bid < SEM_BLOCKS + LBAND_BLOCKS) {
    // ------------- L bands: TV (v+h) + exposure; 2 bands per block ---------
    const int lidx = bid - SEM_BLOCKS;      // 0..255
    const int sub = tid >> 8;               // 0/1 -> band
    const int stid = tid & 255;
    const int band = lidx * 2 + sub;        // 0..511
    const int b = band >> 5;                // 0..15
    const int pr = band & 31;               // patch row
    const int half = stid >> 7;             // 0..1
    const int c4 = stid & 127;              // f4 column
    const int row0 = pr * 16 + half * 8;
    const float* Lb = L + (size_t)b * HW;
    const float4* L4b = (const float4*)Lb;
    __shared__ float part[2][2][128];
    __shared__ float redv[2][4], redh[2][4];

    float sv = 0.f, sh = 0.f, ps = 0.f;
    float4 cur = L4b[row0 * 128 + c4];
#pragma unroll
    for (int r = 0; r < 8; ++r) {
      sh += fabsf(cur.x - cur.y) + fabsf(cur.y - cur.z) + fabsf(cur.z - cur.w);
      float nx = __shfl_down(cur.x, 1);  // next f4's .x, same row
      if (lane == 63 && c4 < 127) nx = Lb[(row0 + r) * 512 + c4 * 4 + 4];
      if (c4 < 127) sh += fabsf(cur.w - nx);
      ps += (cur.x + cur.y) + (cur.z + cur.w);
      int nr = row0 + r + 1;
      if (nr < 512) {
        float4 nxt = L4b[nr * 128 + c4];
        sv += fabsf(cur.x - nxt.x) + fabsf(cur.y - nxt.y) +
              fabsf(cur.z - nxt.z) + fabsf(cur.w - nxt.w);
        cur = nxt;
      }
    }
    part[sub][half][c4] = ps;
    sv = wave_reduce(sv);
    sh = wave_reduce(sh);
    int wv2 = stid >> 6;  // wave within sub-block: 0..3
    if (lane == 0) { redv[sub][wv2] = sv; redh[sub][wv2] = sh; }
    __syncthreads();
    if (stid == 0) {
      atomicAdd(&ws[1],
                (redv[sub][0] + redv[sub][1]) + (redv[sub][2] + redv[sub][3]));
      atomicAdd(&ws[2],
                (redh[sub][0] + redh[sub][1]) + (redh[sub][2] + redh[sub][3]));
    }
    float e = 0.f;
    if (stid < 32) {  // patch p = stid covers f4 cols [4p, 4p+4)
      float s = 0.f;
#pragma unroll
      for (int h = 0; h < 2; ++h)
#pragma unroll
        for (int q = 0; q < 4; ++q) s += part[sub][h][stid * 4 + q];
      float d = s * (1.0f / 256.0f) - 0.6f;
      e = d * d;
    }
    e = wave_reduce(e);
    if (stid == 0) atomicAdd(&ws[0], e);
    return;
  }

  {
    // ------------- color: per (b,c) channel sums of I_enh ------------------
    const int cid = bid - (SEM_BLOCKS + LBAND_BLOCKS);  // 0..383
    const int slice = cid >> 3;             // 0..47
    const int xb8 = cid & 7;
    const float4* I4 = (const float4*)(I + (size_t)slice * HW);
    float s = 0.f;
    int i = xb8 * 8192 + tid;
#pragma unroll 4
    for (int it = 0; it < 16; ++it, i += 512) {
      float4 v = I4[i];
      s += (v.x + v.y) + (v.z + v.w);
    }
    s = wave_reduce(s);
    __shared__ float red[8];
    int wv = tid >> 6;
    if (lane == 0) red[wv] = s;
    __syncthreads();
    if (tid == 0) {
      float t = ((red[0] + red[1]) + (red[2] + red[3])) +
                ((red[4] + red[5]) + (red[6] + red[7]));
      atomicAdd(&ws[3 + slice], t);
    }
  }
}

// ---------------- final combine ----------------
__global__ __launch_bounds__(256) void final_kernel(const float* __restrict__ ws,
                                                    float* __restrict__ out) {
  __shared__ float red[256];
  int t = threadIdx.x;
  float sem = 0.f;
  if (t < 128) {
    const float* s = ws + 51 + t * 11;
    float n = s[0] + 1e-6f;
    float v = 0.f;
#pragma unroll
    for (int c = 0; c < 3; ++c) {
      float mean = s[2 + c] / n;
      v += s[8 + c] - 2.0f * mean * s[5 + c] + mean * mean * s[1];
    }
    sem = v / n;
  }
  red[t] = sem;
  __syncthreads();
  for (int s = 128; s > 0; s >>= 1) {
    if (t < s) red[t] += red[t + s];
    __syncthreads();
  }
  if (t == 0) {
    float L_sem = red[0] / 16.0f;
    float L_exp = ws[0] / (float)NPATCH;
    float L_tv = ws[1] / (16.0f * 511.0f * 512.0f) +
                 ws[2] / (16.0f * 512.0f * 511.0f);
    float L_color = 0.f;
#pragma unroll
    for (int b = 0; b < 16; ++b) {
      float r = ws[3 + b * 3 + 0] * (1.0f / (float)HW);
      float g = ws[3 + b * 3 + 1] * (1.0f / (float)HW);
      float bl = ws[3 + b * 3 + 2] * (1.0f / (float)HW);
      L_color += (r - g) * (r - g) + (r - bl) * (r - bl) + (g - bl) * (g - bl);
    }
    L_color *= (1.0f / 16.0f);
    out[0] = 10.0f * L_exp + 1.0f * L_tv + 10.0f * L_color + 50.0f * L_sem;
  }
}

extern "C" void kernel_launch(void* const* d_in, const int* in_sizes, int n_in,
                              void* d_out, int out_size, void* d_ws, size_t ws_size,
                              hipStream_t stream) {
  const float* L     = (const float*)d_in[0];  // (16,1,512,512)
  const float* R     = (const float*)d_in[1];  // (16,3,512,512)
  const float* I_enh = (const float*)d_in[2];  // (16,3,512,512)
  const float* M     = (const float*)d_in[3];  // (16,8,512,512)
  float* out = (float*)d_out;
  float* ws  = (float*)d_ws;

  (void)hipMemsetAsync(d_ws, 0, WS_FLOATS * sizeof(float), stream);
  mega_kernel<<<TOTAL_BLOCKS, 512, 0, stream>>>(L, R, I_enh, M, ws);
  final_kernel<<<1, 256, 0, stream>>>(ws, out);
}